// Round 1
// baseline (169.672 us; speedup 1.0000x reference)
//
#include <hip/hip_runtime.h>
#include <hip/hip_bf16.h>

#define V 17
#define C_DIM 256
#define T_DIM 64
#define TV 1088        // T*V
#define CTV 278528     // C*T*V
#define M_TOT 69632    // N*T*V rows
#define BM 64
#define BKP 40         // padded halves per LDS row (80B -> 20-bank stride)

typedef __attribute__((ext_vector_type(8))) short short8;
typedef __attribute__((ext_vector_type(4))) float f32x4;

static __device__ inline short f2bf(float f) {
    union { __hip_bfloat16 b; short s; } u;
    u.b = __float2bfloat16(f);
    return u.s;
}

// ws layout (bytes):
//   0      : wtb   (65536 bf16 = 131072 B)  blocked B^T: wtb[(kc*256+d)*32+kk] = W[kc*32+kk][d]
//   131072 : g     (4352 f32)   tanh(fm)+1
//   148480 : scale (4352 f32)   gamma/sqrt(var+eps)
//   165888 : off   (4352 f32)   (lin_b[d]-mean)*scale+beta
__global__ __launch_bounds__(256) void prep_kernel(
    const float* __restrict__ fm, const float* __restrict__ W,
    const float* __restrict__ lb, const float* __restrict__ gamma,
    const float* __restrict__ beta, const float* __restrict__ mean,
    const float* __restrict__ var,
    __hip_bfloat16* __restrict__ wtb, float* __restrict__ g,
    float* __restrict__ scale, float* __restrict__ off)
{
    int i = blockIdx.x * 256 + threadIdx.x;   // 65536 threads
    int c = i >> 8, d = i & 255;
    float w = W[i];
    wtb[((c >> 5) * 256 + d) * 32 + (c & 31)] = __float2bfloat16(w);
    if (i < V * C_DIM) {
        g[i] = tanhf(fm[i]) + 1.0f;
        float sc = gamma[i] * rsqrtf(var[i] + 1e-5f);
        scale[i] = sc;
        int dd = i & 255;
        off[i] = (lb[dd] - mean[i]) * sc + beta[i];
    }
}

__global__ __launch_bounds__(256) void shiftgcn_kernel(
    const float* __restrict__ x0, const __hip_bfloat16* __restrict__ wtb,
    const float* __restrict__ g, const float* __restrict__ scale,
    const float* __restrict__ off, float* __restrict__ out)
{
    __shared__ short As[BM * BKP];       // [row][kk]
    __shared__ short Bs[C_DIM * BKP];    // [d][kk]

    const int tid  = threadIdx.x;
    const int lane = tid & 63;
    const int wv   = tid >> 6;
    const int r0   = blockIdx.x * BM;

    // A-staging row owned by this thread (one row x 8 k-elements per wave)
    const int r  = r0 + lane;
    const int nt = r / V;
    const int u  = r - nt * V;
    const float* xrow = x0 + (nt >> 6) * CTV + (nt & 63) * V;  // + c*TV + joint
    const float* grow = g + u * C_DIM;

    f32x4 acc[4][4];
    #pragma unroll
    for (int mi = 0; mi < 4; ++mi)
        #pragma unroll
        for (int ni = 0; ni < 4; ++ni)
            acc[mi][ni] = (f32x4){0.f, 0.f, 0.f, 0.f};

    const int l15 = lane & 15;
    const int lq  = lane >> 4;

    for (int kc = 0; kc < 8; ++kc) {
        // ---- stage A: gather + gate + bf16 cast (this thread: row=lane, kk = wv*8..wv*8+7)
        const int cbase = kc * 32 + wv * 8;
        float4 g0 = *(const float4*)(grow + cbase);
        float4 g1 = *(const float4*)(grow + cbase + 4);
        float gv[8] = {g0.x, g0.y, g0.z, g0.w, g1.x, g1.y, g1.z, g1.w};
        int m = (u + cbase) % V;          // input joint (u+c) mod 17, incremental
        short av[8];
        #pragma unroll
        for (int i = 0; i < 8; ++i) {
            float xv = xrow[(cbase + i) * TV + m];
            m = (m == V - 1) ? 0 : m + 1;
            av[i] = f2bf(xv * gv[i]);
        }
        short8 apack = {av[0], av[1], av[2], av[3], av[4], av[5], av[6], av[7]};
        *(short8*)(As + lane * BKP + wv * 8) = apack;

        // ---- stage B^T tile: contiguous 16KB from blocked wtb
        const short8* wsrc = (const short8*)(wtb + kc * 8192);
        #pragma unroll
        for (int q = 0; q < 4; ++q) {
            int j = q * 256 + tid;                 // chunk = 8 halves; d = j>>2, kk0 = (j&3)*8
            short8 bv = wsrc[j];
            *(short8*)(Bs + (j >> 2) * BKP + (j & 3) * 8) = bv;
        }
        __syncthreads();

        // ---- MFMA: wave wv owns cols [wv*64, wv*64+64), all 64 rows
        short8 afr[4], bfr[4];
        #pragma unroll
        for (int mi = 0; mi < 4; ++mi)
            afr[mi] = *(const short8*)(As + (mi * 16 + l15) * BKP + lq * 8);
        #pragma unroll
        for (int ni = 0; ni < 4; ++ni)
            bfr[ni] = *(const short8*)(Bs + (wv * 64 + ni * 16 + l15) * BKP + lq * 8);
        #pragma unroll
        for (int mi = 0; mi < 4; ++mi)
            #pragma unroll
            for (int ni = 0; ni < 4; ++ni)
                acc[mi][ni] = __builtin_amdgcn_mfma_f32_16x16x32_bf16(
                    afr[mi], bfr[ni], acc[mi][ni], 0, 0, 0);
        __syncthreads();
    }

    // ---- epilogue: shift_out scatter + BN + residual + relu
    // D frag: col = lane&15, row = (lane>>4)*4 + reg  [guide §3, m89-verified]
    #pragma unroll
    for (int mi = 0; mi < 4; ++mi) {
        #pragma unroll
        for (int rg = 0; rg < 4; ++rg) {
            const int rr  = r0 + mi * 16 + lq * 4 + rg;
            const int nt2 = rr / V;
            const int u2  = rr - nt2 * V;
            const int b2  = (nt2 >> 6) * CTV + (nt2 & 63) * V;
            #pragma unroll
            for (int ni = 0; ni < 4; ++ni) {
                const int d = wv * 64 + ni * 16 + l15;
                int v = u2 + d;
                v = v % V;                         // output joint
                const int kbn = v * C_DIM + d;
                float z = acc[mi][ni][rg] * scale[kbn] + off[kbn];
                const int idx = b2 + d * TV + v;   // (n,d,t,v) flat
                z += x0[idx];
                out[idx] = fmaxf(z, 0.f);
            }
        }
    }
}

extern "C" void kernel_launch(void* const* d_in, const int* in_sizes, int n_in,
                              void* d_out, int out_size, void* d_ws, size_t ws_size,
                              hipStream_t stream)
{
    const float* x0    = (const float*)d_in[0];
    const float* fm    = (const float*)d_in[1];
    const float* W     = (const float*)d_in[2];
    const float* lb    = (const float*)d_in[3];
    const float* gamma = (const float*)d_in[4];
    const float* beta  = (const float*)d_in[5];
    const float* mean  = (const float*)d_in[6];
    const float* var   = (const float*)d_in[7];
    float* out = (float*)d_out;

    char* ws = (char*)d_ws;
    __hip_bfloat16* wtb = (__hip_bfloat16*)ws;
    float* g     = (float*)(ws + 131072);
    float* scale = (float*)(ws + 148480);
    float* off   = (float*)(ws + 165888);

    prep_kernel<<<256, 256, 0, stream>>>(fm, W, lb, gamma, beta, mean, var,
                                         wtb, g, scale, off);
    shiftgcn_kernel<<<M_TOT / BM, 256, 0, stream>>>(x0, wtb, g, scale, off, out);
}

// Round 2
// 142.032 us; speedup vs baseline: 1.1946x; 1.1946x over previous
//
#include <hip/hip_runtime.h>
#include <hip/hip_bf16.h>

#define V 17
#define C_DIM 256
#define TV 1088        // T*V
#define CTV 278528     // C*T*V
#define BKP 40         // A LDS pitch in halves (80B -> 20-bank stride, 2-way = free)
#define YP 76          // y LDS pitch in floats (304B, 16B-aligned, 12-bank stride)

typedef __attribute__((ext_vector_type(8))) short short8;
typedef __attribute__((ext_vector_type(4))) float f32x4;

static __device__ inline short f2bfs(float f) {
    union { __hip_bfloat16 b; short s; } u;
    u.b = __float2bfloat16(f);
    return u.s;
}

// ws layout (bytes):
//   0      : wtb   (65536 bf16)  blocked B^T: wtb[(kc*256+d)*32+kk] = W[kc*32+kk][d]
//   131072 : g     (4352 f32)    tanh(fm)+1
//   148480 : scale (4352 f32)    gamma/sqrt(var+eps)
//   165888 : off   (4352 f32)    (lin_b[d]-mean)*scale+beta
__global__ __launch_bounds__(256) void prep_kernel(
    const float* __restrict__ fm, const float* __restrict__ W,
    const float* __restrict__ lb, const float* __restrict__ gamma,
    const float* __restrict__ beta, const float* __restrict__ mean,
    const float* __restrict__ var,
    __hip_bfloat16* __restrict__ wtb, float* __restrict__ g,
    float* __restrict__ scale, float* __restrict__ off)
{
    int i = blockIdx.x * 256 + threadIdx.x;   // 65536 threads
    int c = i >> 8, d = i & 255;
    float w = W[i];
    wtb[((c >> 5) * 256 + d) * 32 + (c & 31)] = __float2bfloat16(w);
    if (i < V * C_DIM) {
        g[i] = tanhf(fm[i]) + 1.0f;
        float sc = gamma[i] * rsqrtf(var[i] + 1e-5f);
        scale[i] = sc;
        int dd = i & 255;
        off[i] = (lb[dd] - mean[i]) * sc + beta[i];
    }
}

// Block: nt0 = 4*blockIdx (4 whole t-groups, 68 rows, padded to 80), all 256 d.
__global__ __launch_bounds__(256) void shiftgcn_kernel(
    const float* __restrict__ x0, const __hip_bfloat16* __restrict__ wtb,
    const float* __restrict__ g, const float* __restrict__ scale,
    const float* __restrict__ off, float* __restrict__ out)
{
    // union: gather phase {As 6400B + Gs 17408B} / epilogue {Ys 19456B}
    __shared__ __align__(16) char smem[24064];
    short* As = (short*)smem;                 // [80 rows][BKP halves]
    float* Gs = (float*)(smem + 6400);        // gate f32 [17][256]
    float* Ys = (float*)smem;                 // [4 waves][16 d][YP floats]

    const int tid  = threadIdx.x;
    const int lane = tid & 63;
    const int wv   = tid >> 6;
    const int l15  = lane & 15;
    const int lq   = lane >> 4;

    const int nt0 = blockIdx.x * 4;
    const int n   = nt0 >> 6;
    const int tb  = nt0 & 63;                 // multiple of 4
    const float* xplane = x0 + n * CTV + tb * V;   // + c*TV + pos

    // zero the 12 pad rows (68..79) once; stage gate f32 to LDS (coalesced)
    if (tid < 60) ((short8*)(As + 68 * BKP))[tid] = (short8)0;
    for (int j = tid; j < 1088; j += 256)
        ((float4*)Gs)[j] = ((const float4*)g)[j];
    __syncthreads();

    f32x4 acc[5][4];
    #pragma unroll
    for (int mi = 0; mi < 5; ++mi)
        #pragma unroll
        for (int ni = 0; ni < 4; ++ni)
            acc[mi][ni] = (f32x4){0.f, 0.f, 0.f, 0.f};

    for (int kc = 0; kc < 8; ++kc) {
        // ---- A gather: 544 coalesced float4 loads (32 c x 17 float4 windows),
        //      shift-permute + gate applied on the LDS-write side.
        #pragma unroll
        for (int it = 0; it < 3; ++it) {
            int j = it * 256 + tid;
            if (j < 544) {
                int cl = j / 17;               // 0..31 (k index within tile)
                int f4 = j - cl * 17;          // 0..16
                int c  = kc * 32 + cl;
                float4 xv = *(const float4*)(xplane + c * TV + f4 * 4);
                int cm  = c % 17;
                int pos = f4 * 4;
                int tl  = pos / 17;
                int m   = pos - tl * 17;       // joint index in plane
                float vals[4] = {xv.x, xv.y, xv.z, xv.w};
                #pragma unroll
                for (int e = 0; e < 4; ++e) {
                    int u = m - cm; if (u < 0) u += 17;   // source row-joint
                    As[(tl * V + u) * BKP + cl] = f2bfs(vals[e] * Gs[u * 256 + c]);
                    if (++m == 17) { m = 0; ++tl; }
                }
            }
        }
        // ---- B fragments straight from global (128KB blocked wtb, L2-resident),
        //      issued before the barrier so latency hides under it.
        short8 bfr[4];
        #pragma unroll
        for (int ni = 0; ni < 4; ++ni)
            bfr[ni] = *(const short8*)(wtb +
                ((kc * 256 + wv * 64 + ni * 16 + l15) << 5) + lq * 8);
        __syncthreads();

        short8 afr[5];
        #pragma unroll
        for (int mi = 0; mi < 5; ++mi)
            afr[mi] = *(const short8*)(As + (mi * 16 + l15) * BKP + lq * 8);
        #pragma unroll
        for (int mi = 0; mi < 5; ++mi)
            #pragma unroll
            for (int ni = 0; ni < 4; ++ni)
                acc[mi][ni] = __builtin_amdgcn_mfma_f32_16x16x32_bf16(
                    afr[mi], bfr[ni], acc[mi][ni], 0, 0, 0);
        __syncthreads();
    }

    // ---- epilogue: per n-tile, transpose acc through per-wave LDS, then
    //      coalesced float4 BN + residual + relu writes (68-float d-windows).
    float* yw = Ys + wv * 16 * YP;
    const int dbase0 = wv * 64;
    #pragma unroll
    for (int ni = 0; ni < 4; ++ni) {
        const int d_l = dbase0 + ni * 16 + l15;
        const int dm  = d_l % 17;
        #pragma unroll
        for (int mi = 0; mi < 5; ++mi) {
            #pragma unroll
            for (int rg = 0; rg < 4; ++rg) {
                int row = mi * 16 + lq * 4 + rg;     // D frag: col=l15, row=lq*4+rg
                if (row < 68) {
                    int tl = row / V;
                    int u  = row - tl * V;
                    int v  = u + dm; if (v >= V) v -= V;
                    yw[l15 * YP + tl * V + v] = acc[mi][ni][rg];
                }
            }
        }
        __syncthreads();
        #pragma unroll
        for (int it = 0; it < 5; ++it) {
            int j = it * 64 + lane;                  // 272 float4 per wave-tile
            if (j < 272) {
                int dl  = j / 17;                    // 0..15
                int p4  = j - dl * 17;               // 0..16
                int d   = dbase0 + ni * 16 + dl;
                int pos = p4 * 4;
                int base = n * CTV + d * TV + tb * V + pos;
                float4 yv = *(const float4*)(yw + dl * YP + pos);
                float4 xv = *(const float4*)(x0 + base);
                float yy[4] = {yv.x, yv.y, yv.z, yv.w};
                float xx[4] = {xv.x, xv.y, xv.z, xv.w};
                int v = pos % V;
                float rr[4];
                #pragma unroll
                for (int e = 0; e < 4; ++e) {
                    int kbn = v * C_DIM + d;
                    rr[e] = fmaxf(yy[e] * scale[kbn] + off[kbn] + xx[e], 0.f);
                    if (++v == V) v = 0;
                }
                *(float4*)(out + base) = (float4){rr[0], rr[1], rr[2], rr[3]};
            }
        }
        __syncthreads();
    }
}

extern "C" void kernel_launch(void* const* d_in, const int* in_sizes, int n_in,
                              void* d_out, int out_size, void* d_ws, size_t ws_size,
                              hipStream_t stream)
{
    const float* x0    = (const float*)d_in[0];
    const float* fm    = (const float*)d_in[1];
    const float* W     = (const float*)d_in[2];
    const float* lb    = (const float*)d_in[3];
    const float* gamma = (const float*)d_in[4];
    const float* beta  = (const float*)d_in[5];
    const float* mean  = (const float*)d_in[6];
    const float* var   = (const float*)d_in[7];
    float* out = (float*)d_out;

    char* ws = (char*)d_ws;
    __hip_bfloat16* wtb = (__hip_bfloat16*)ws;
    float* g     = (float*)(ws + 131072);
    float* scale = (float*)(ws + 148480);
    float* off   = (float*)(ws + 165888);

    prep_kernel<<<256, 256, 0, stream>>>(fm, W, lb, gamma, beta, mean, var,
                                         wtb, g, scale, off);
    shiftgcn_kernel<<<1024, 256, 0, stream>>>(x0, wtb, g, scale, off, out);
}

// Round 3
// 119.330 us; speedup vs baseline: 1.4219x; 1.1902x over previous
//
#include <hip/hip_runtime.h>
#include <hip/hip_bf16.h>

#define V 17
#define C_DIM 256
#define TV 1088        // T*V
#define CTV 278528     // C*T*V
#define KP 264         // A LDS pitch in halves (528B; row stride = 4 banks -> even spread)
#define YP 76          // y LDS pitch in floats

typedef __attribute__((ext_vector_type(8))) short short8;
typedef __attribute__((ext_vector_type(4))) float f32x4;

static __device__ inline short f2bfs(float f) {
    union { __hip_bfloat16 b; short s; } u;
    u.b = __float2bfloat16(f);
    return u.s;
}

// ws layout (bytes):
//   0      : wtb   (65536 bf16)  blocked B^T: wtb[(kc*256+d)*32+kk] = W[kc*32+kk][d]
//   131072 : g     (4352 f32)    tanh(fm)+1
//   148480 : scale (4352 f32)    gamma/sqrt(var+eps)
//   165888 : off   (4352 f32)    (lin_b[d]-mean)*scale+beta
__global__ __launch_bounds__(256) void prep_kernel(
    const float* __restrict__ fm, const float* __restrict__ W,
    const float* __restrict__ lb, const float* __restrict__ gamma,
    const float* __restrict__ beta, const float* __restrict__ mean,
    const float* __restrict__ var,
    __hip_bfloat16* __restrict__ wtb, float* __restrict__ g,
    float* __restrict__ scale, float* __restrict__ off)
{
    int i = blockIdx.x * 256 + threadIdx.x;   // 65536 threads
    int c = i >> 8, d = i & 255;
    float w = W[i];
    wtb[((c >> 5) * 256 + d) * 32 + (c & 31)] = __float2bfloat16(w);
    if (i < V * C_DIM) {
        g[i] = tanhf(fm[i]) + 1.0f;
        float sc = gamma[i] * rsqrtf(var[i] + 1e-5f);
        scale[i] = sc;
        int dd = i & 255;
        off[i] = (lb[dd] - mean[i]) * sc + beta[i];
    }
}

// Block: nt0 = 4*blockIdx (4 whole t-groups, 68 rows, padded to 80), all 256 d.
// Phase 1: stage FULL-K gated A-tile (68x256 bf16) into LDS, one barrier.
// Phase 2: 160 MFMAs, barrier-free (B frags from L2-resident blocked wtb).
// Phase 3: round-2 epilogue (per-wave LDS transpose -> coalesced float4 I/O).
__global__ __launch_bounds__(256) void shiftgcn_kernel(
    const float* __restrict__ x0, const __hip_bfloat16* __restrict__ wtb,
    const float* __restrict__ g, const float* __restrict__ scale,
    const float* __restrict__ off, float* __restrict__ out)
{
    __shared__ __align__(16) char smem[80 * KP * 2];   // 42240 B
    short* As = (short*)smem;                 // [80 rows][KP halves]
    float* Ys = (float*)smem;                 // epilogue union: [4 waves][16 d][YP]

    const int tid  = threadIdx.x;
    const int lane = tid & 63;
    const int wv   = tid >> 6;
    const int l15  = lane & 15;
    const int lq   = lane >> 4;

    const int nt0 = blockIdx.x * 4;
    const int n   = nt0 >> 6;
    const int tb  = nt0 & 63;                 // multiple of 4
    const float* xplane = x0 + n * CTV + tb * V;   // + c*TV + tl*V + joint

    // zero pad rows 68..79 (12 rows * 264 halves = 396 short8)
    for (int j = tid; j < 396; j += 256)
        ((short8*)(As + 68 * KP))[j] = (short8)0;

    // ---- Phase 1: stage all K. 2176 tasks = 32 k-chunks x 68 rows.
    // Task: 8 scalar x0 loads along c (coalesced across lanes: consecutive rows
    // at fixed c read a contiguous rotated 17-float window), gate from global
    // (L1-resident), one contiguous short8 LDS write (zero-conflict layout).
    #pragma unroll
    for (int it = 0; it < 9; ++it) {
        int t = it * 256 + tid;
        if (t < 2176) {
            int kkc = t / 68;                  // 0..31
            int r   = t - kkc * 68;            // 0..67
            int tl  = r / 17;
            int u   = r - tl * 17;
            int c0  = kkc * 8;
            const float* gp = g + u * C_DIM + c0;
            float4 g0 = *(const float4*)gp;
            float4 g1 = *(const float4*)(gp + 4);
            float gg[8] = {g0.x, g0.y, g0.z, g0.w, g1.x, g1.y, g1.z, g1.w};
            const float* xb = xplane + tl * V;
            int mm = u + c0 % V;               // (u + c0) % 17, c0 = 8*kkc
            mm = (u + c0) % V;
            float xv[8];
            #pragma unroll
            for (int i = 0; i < 8; ++i) {
                xv[i] = xb[(c0 + i) * TV + mm];
                mm = (mm == V - 1) ? 0 : mm + 1;
            }
            short av[8];
            #pragma unroll
            for (int i = 0; i < 8; ++i) av[i] = f2bfs(xv[i] * gg[i]);
            *(short8*)(As + r * KP + c0) =
                (short8){av[0], av[1], av[2], av[3], av[4], av[5], av[6], av[7]};
        }
    }
    __syncthreads();

    // ---- Phase 2: MFMA, no barriers. Wave wv owns cols [wv*64, wv*64+64).
    f32x4 acc[5][4];
    #pragma unroll
    for (int mi = 0; mi < 5; ++mi)
        #pragma unroll
        for (int ni = 0; ni < 4; ++ni)
            acc[mi][ni] = (f32x4){0.f, 0.f, 0.f, 0.f};

    #pragma unroll
    for (int kc = 0; kc < 8; ++kc) {
        short8 bfr[4];
        #pragma unroll
        for (int ni = 0; ni < 4; ++ni)
            bfr[ni] = *(const short8*)(wtb +
                ((kc * 256 + wv * 64 + ni * 16 + l15) << 5) + lq * 8);
        short8 afr[5];
        #pragma unroll
        for (int mi = 0; mi < 5; ++mi)
            afr[mi] = *(const short8*)(As + (mi * 16 + l15) * KP + kc * 32 + lq * 8);
        #pragma unroll
        for (int mi = 0; mi < 5; ++mi)
            #pragma unroll
            for (int ni = 0; ni < 4; ++ni)
                acc[mi][ni] = __builtin_amdgcn_mfma_f32_16x16x32_bf16(
                    afr[mi], bfr[ni], acc[mi][ni], 0, 0, 0);
    }
    __syncthreads();   // As dead; Ys live

    // ---- Phase 3: epilogue — per-wave LDS transpose, then coalesced
    //      float4 BN + residual + relu (68-float d-windows).
    float* yw = Ys + wv * 16 * YP;
    const int dbase0 = wv * 64;
    #pragma unroll
    for (int ni = 0; ni < 4; ++ni) {
        const int d_l = dbase0 + ni * 16 + l15;
        const int dm  = d_l % V;
        #pragma unroll
        for (int mi = 0; mi < 5; ++mi) {
            #pragma unroll
            for (int rg = 0; rg < 4; ++rg) {
                int row = mi * 16 + lq * 4 + rg;     // D frag: col=l15, row=lq*4+rg
                if (row < 68) {
                    int tl = row / V;
                    int u  = row - tl * V;
                    int v  = u + dm; if (v >= V) v -= V;
                    yw[l15 * YP + tl * V + v] = acc[mi][ni][rg];
                }
            }
        }
        __syncthreads();
        #pragma unroll
        for (int it = 0; it < 5; ++it) {
            int j = it * 64 + lane;                  // 272 float4 per wave-tile
            if (j < 272) {
                int dl  = j / 17;                    // 0..15
                int p4  = j - dl * 17;               // 0..16
                int d   = dbase0 + ni * 16 + dl;
                int pos = p4 * 4;
                int base = n * CTV + d * TV + tb * V + pos;
                float4 yv = *(const float4*)(yw + dl * YP + pos);
                float4 xv = *(const float4*)(x0 + base);
                float yy[4] = {yv.x, yv.y, yv.z, yv.w};
                float xx[4] = {xv.x, xv.y, xv.z, xv.w};
                int v = pos % V;
                float rr[4];
                #pragma unroll
                for (int e = 0; e < 4; ++e) {
                    int kbn = v * C_DIM + d;
                    rr[e] = fmaxf(yy[e] * scale[kbn] + off[kbn] + xx[e], 0.f);
                    if (++v == V) v = 0;
                }
                *(float4*)(out + base) = (float4){rr[0], rr[1], rr[2], rr[3]};
            }
        }
        __syncthreads();
    }
}

extern "C" void kernel_launch(void* const* d_in, const int* in_sizes, int n_in,
                              void* d_out, int out_size, void* d_ws, size_t ws_size,
                              hipStream_t stream)
{
    const float* x0    = (const float*)d_in[0];
    const float* fm    = (const float*)d_in[1];
    const float* W     = (const float*)d_in[2];
    const float* lb    = (const float*)d_in[3];
    const float* gamma = (const float*)d_in[4];
    const float* beta  = (const float*)d_in[5];
    const float* mean  = (const float*)d_in[6];
    const float* var   = (const float*)d_in[7];
    float* out = (float*)d_out;

    char* ws = (char*)d_ws;
    __hip_bfloat16* wtb = (__hip_bfloat16*)ws;
    float* g     = (float*)(ws + 131072);
    float* scale = (float*)(ws + 148480);
    float* off   = (float*)(ws + 165888);

    prep_kernel<<<256, 256, 0, stream>>>(fm, W, lb, gamma, beta, mean, var,
                                         wtb, g, scale, off);
    shiftgcn_kernel<<<1024, 256, 0, stream>>>(x0, wtb, g, scale, off, out);
}

// Round 4
// 75.714 us; speedup vs baseline: 2.2410x; 1.5761x over previous
//
#include <hip/hip_runtime.h>
#include <hip/hip_bf16.h>

#define V 17
#define C_DIM 256
#define TV 1088        // T*V
#define CTV 278528     // C*T*V
#define KP 264         // A LDS pitch in halves (528B = 16*33: odd 16B-slot stride)
#define YP 76          // y LDS pitch in floats

typedef __attribute__((ext_vector_type(8))) short short8;
typedef __attribute__((ext_vector_type(4))) float f32x4;

static __device__ inline short f2bfs(float f) {
    union { __hip_bfloat16 b; short s; } u;
    u.b = __float2bfloat16(f);
    return u.s;
}

// ws layout (bytes):
//   0      : wtb   (65536 bf16)   blocked B^T: wtb[(kc*256+d)*32+kk] = W[kc*32+kk][d]
//   131072 : g     (4352 f32)     tanh(fm)+1
//   148480 : soff  (4352 float2)  {scale, off} = {gamma*rsqrt(var+eps), (lin_b-mean)*scale+beta}
__global__ __launch_bounds__(256) void prep_kernel(
    const float* __restrict__ fm, const float* __restrict__ W,
    const float* __restrict__ lb, const float* __restrict__ gamma,
    const float* __restrict__ beta, const float* __restrict__ mean,
    const float* __restrict__ var,
    __hip_bfloat16* __restrict__ wtb, float* __restrict__ g,
    float2* __restrict__ soff)
{
    int i = blockIdx.x * 256 + threadIdx.x;   // 65536 threads
    int c = i >> 8, d = i & 255;
    float w = W[i];
    wtb[((c >> 5) * 256 + d) * 32 + (c & 31)] = __float2bfloat16(w);
    if (i < V * C_DIM) {
        g[i] = tanhf(fm[i]) + 1.0f;
        float sc = gamma[i] * rsqrtf(var[i] + 1e-5f);
        soff[i] = make_float2(sc, (lb[d] - mean[i]) * sc + beta[i]);
    }
}

// Block: nt0 = 4*blockIdx (4 whole t-groups, 68 rows, padded to 80), all 256 d.
// 512 threads / 8 waves; wave wv owns output cols [wv*32, wv*32+32).
// Phase 1: stage FULL-K gated A-tile (68x256 bf16) into LDS, one barrier.
// Phase 2: 80 MFMAs/wave, barrier-free (B frags from L2-resident blocked wtb).
// Phase 3: per-wave LDS transpose -> coalesced float4 BN+residual+relu.
__global__ __launch_bounds__(512, 4) void shiftgcn_kernel(
    const float* __restrict__ x0, const __hip_bfloat16* __restrict__ wtb,
    const float* __restrict__ g, const float2* __restrict__ soff,
    float* __restrict__ out)
{
    __shared__ __align__(16) char smem[80 * KP * 2];   // 42240 B
    short* As = (short*)smem;                 // [80 rows][KP halves]
    float* Ys = (float*)smem;                 // epilogue union: [8 waves][16 d][YP]

    const int tid  = threadIdx.x;
    const int lane = tid & 63;
    const int wv   = tid >> 6;                // 0..7
    const int l15  = lane & 15;
    const int lq   = lane >> 4;

    const int nt0 = blockIdx.x * 4;
    const int n   = nt0 >> 6;
    const int tb  = nt0 & 63;                 // multiple of 4
    const float* xplane = x0 + n * CTV + tb * V;   // + c*TV + tl*V + joint

    // zero pad rows 68..79 (12 rows * 264 halves = 396 short8)
    if (tid < 396) ((short8*)(As + 68 * KP))[tid] = (short8)0;

    // ---- Phase 1: stage all K. 2176 tasks = 32 k-chunks x 68 rows.
    #pragma unroll
    for (int it = 0; it < 5; ++it) {
        int t = it * 512 + tid;
        if (t < 2176) {
            int kkc = t / 68;                  // 0..31
            int r   = t - kkc * 68;            // 0..67
            int tl  = r / 17;
            int u   = r - tl * 17;
            int c0  = kkc * 8;
            const float* gp = g + u * C_DIM + c0;
            float4 g0 = *(const float4*)gp;
            float4 g1 = *(const float4*)(gp + 4);
            float gg[8] = {g0.x, g0.y, g0.z, g0.w, g1.x, g1.y, g1.z, g1.w};
            const float* xb = xplane + tl * V;
            int mm = (u + c0) % V;
            float xv[8];
            #pragma unroll
            for (int i = 0; i < 8; ++i) {
                xv[i] = xb[(c0 + i) * TV + mm];
                mm = (mm == V - 1) ? 0 : mm + 1;
            }
            short av[8];
            #pragma unroll
            for (int i = 0; i < 8; ++i) av[i] = f2bfs(xv[i] * gg[i]);
            *(short8*)(As + r * KP + c0) =
                (short8){av[0], av[1], av[2], av[3], av[4], av[5], av[6], av[7]};
        }
    }
    __syncthreads();

    // ---- Phase 2: MFMA, no barriers. Wave wv owns cols [wv*32, wv*32+32).
    f32x4 acc[5][2];
    #pragma unroll
    for (int mi = 0; mi < 5; ++mi)
        #pragma unroll
        for (int ni = 0; ni < 2; ++ni)
            acc[mi][ni] = (f32x4){0.f, 0.f, 0.f, 0.f};

    #pragma unroll
    for (int kc = 0; kc < 8; ++kc) {
        short8 bfr[2];
        #pragma unroll
        for (int ni = 0; ni < 2; ++ni)
            bfr[ni] = *(const short8*)(wtb +
                ((kc * 256 + wv * 32 + ni * 16 + l15) << 5) + lq * 8);
        short8 afr[5];
        #pragma unroll
        for (int mi = 0; mi < 5; ++mi)
            afr[mi] = *(const short8*)(As + (mi * 16 + l15) * KP + kc * 32 + lq * 8);
        #pragma unroll
        for (int mi = 0; mi < 5; ++mi)
            #pragma unroll
            for (int ni = 0; ni < 2; ++ni)
                acc[mi][ni] = __builtin_amdgcn_mfma_f32_16x16x32_bf16(
                    afr[mi], bfr[ni], acc[mi][ni], 0, 0, 0);
    }
    __syncthreads();   // As dead; Ys live

    // ---- Phase 3: epilogue — per-wave LDS transpose, then coalesced
    //      float4 BN + residual + relu (68-float d-windows).
    float* yw = Ys + wv * 16 * YP;
    const int dbase0 = wv * 32;
    #pragma unroll
    for (int ni = 0; ni < 2; ++ni) {
        const int d_l = dbase0 + ni * 16 + l15;
        const int dm  = d_l % V;
        #pragma unroll
        for (int mi = 0; mi < 5; ++mi) {
            #pragma unroll
            for (int rg = 0; rg < 4; ++rg) {
                int row = mi * 16 + lq * 4 + rg;     // D frag: col=l15, row=lq*4+rg
                if (row < 68) {
                    int tl = row / V;
                    int u  = row - tl * V;
                    int v  = u + dm; if (v >= V) v -= V;
                    yw[l15 * YP + tl * V + v] = acc[mi][ni][rg];
                }
            }
        }
        __syncthreads();
        #pragma unroll
        for (int it = 0; it < 5; ++it) {
            int j = it * 64 + lane;                  // 272 float4 per wave-tile
            if (j < 272) {
                int dl  = j / 17;                    // 0..15
                int p4  = j - dl * 17;               // 0..16
                int d   = dbase0 + ni * 16 + dl;
                int pos = p4 * 4;
                int base = n * CTV + d * TV + tb * V + pos;
                float4 yv = *(const float4*)(yw + dl * YP + pos);
                float4 xv = *(const float4*)(x0 + base);
                float yy[4] = {yv.x, yv.y, yv.z, yv.w};
                float xx[4] = {xv.x, xv.y, xv.z, xv.w};
                int v = pos % V;
                float rr[4];
                #pragma unroll
                for (int e = 0; e < 4; ++e) {
                    float2 so = soff[v * C_DIM + d];
                    rr[e] = fmaxf(yy[e] * so.x + so.y + xx[e], 0.f);
                    if (++v == V) v = 0;
                }
                *(float4*)(out + base) = (float4){rr[0], rr[1], rr[2], rr[3]};
            }
        }
        __syncthreads();
    }
}

extern "C" void kernel_launch(void* const* d_in, const int* in_sizes, int n_in,
                              void* d_out, int out_size, void* d_ws, size_t ws_size,
                              hipStream_t stream)
{
    const float* x0    = (const float*)d_in[0];
    const float* fm    = (const float*)d_in[1];
    const float* W     = (const float*)d_in[2];
    const float* lb    = (const float*)d_in[3];
    const float* gamma = (const float*)d_in[4];
    const float* beta  = (const float*)d_in[5];
    const float* mean  = (const float*)d_in[6];
    const float* var   = (const float*)d_in[7];
    float* out = (float*)d_out;

    char* ws = (char*)d_ws;
    __hip_bfloat16* wtb = (__hip_bfloat16*)ws;
    float* g      = (float*)(ws + 131072);
    float2* soff  = (float2*)(ws + 148480);

    prep_kernel<<<256, 256, 0, stream>>>(fm, W, lb, gamma, beta, mean, var,
                                         wtb, g, soff);
    shiftgcn_kernel<<<1024, 512, 0, stream>>>(x0, wtb, g, soff, out);
}

// Round 5
// 73.028 us; speedup vs baseline: 2.3234x; 1.0368x over previous
//
#include <hip/hip_runtime.h>
#include <hip/hip_bf16.h>

#define V 17
#define C_DIM 256
#define TV 1088        // T*V
#define CTV 278528     // C*T*V
#define YP 76          // y LDS pitch in floats

typedef __attribute__((ext_vector_type(8))) short short8;
typedef __attribute__((ext_vector_type(4))) float f32x4;

static __device__ inline short f2bfs(float f) {
    union { __hip_bfloat16 b; short s; } u;
    u.b = __float2bfloat16(f);
    return u.s;
}

// ws layout (bytes):
//   0      : wtb   (65536 bf16)   blocked B^T: wtb[(kc*256+d)*32+kk] = W[kc*32+kk][d]
//   131072 : g     (4352 f32)     tanh(fm)+1
//   148480 : soff  (4352 float2)  {scale, off}
__global__ __launch_bounds__(256) void prep_kernel(
    const float* __restrict__ fm, const float* __restrict__ W,
    const float* __restrict__ lb, const float* __restrict__ gamma,
    const float* __restrict__ beta, const float* __restrict__ mean,
    const float* __restrict__ var,
    __hip_bfloat16* __restrict__ wtb, float* __restrict__ g,
    float2* __restrict__ soff)
{
    int i = blockIdx.x * 256 + threadIdx.x;   // 65536 threads
    int c = i >> 8, d = i & 255;
    float w = W[i];
    wtb[((c >> 5) * 256 + d) * 32 + (c & 31)] = __float2bfloat16(w);
    if (i < V * C_DIM) {
        g[i] = tanhf(fm[i]) + 1.0f;
        float sc = gamma[i] * rsqrtf(var[i] + 1e-5f);
        soff[i] = make_float2(sc, (lb[d] - mean[i]) * sc + beta[i]);
    }
}

// Block: 4 whole t-groups (68 rows, padded to 80), all 256 d. 512 thr / 8 waves.
// A-tile LDS: [80 rows][256 halves] with 16B-slot XOR swizzle (slot ^= row&7)
// -> 40960 B total (union with epilogue Ys) -> 4 blocks/CU.
// XCD swizzle: consecutive work-tiles land on the same XCD's L2.
__global__ __launch_bounds__(512, 4) void shiftgcn_kernel(
    const float* __restrict__ x0, const __hip_bfloat16* __restrict__ wtb,
    const float* __restrict__ g, const float2* __restrict__ soff,
    float* __restrict__ out)
{
    __shared__ __align__(16) char smem[80 * 256 * 2];   // 40960 B
    short* As = (short*)smem;                 // [80 rows][256 halves], swizzled
    float* Ys = (float*)smem;                 // epilogue union: [8 waves][16 d][YP]

    const int tid  = threadIdx.x;
    const int lane = tid & 63;
    const int wv   = tid >> 6;                // 0..7
    const int l15  = lane & 15;
    const int lq   = lane >> 4;

    // T1: 1024 wg = 8 XCD x 128 contiguous tiles (bijective)
    const int wg  = (blockIdx.x & 7) * 128 + (blockIdx.x >> 3);
    const int nt0 = wg * 4;
    const int n   = nt0 >> 6;
    const int tb  = nt0 & 63;                 // multiple of 4
    const float* xplane = x0 + n * CTV + tb * V;   // + c*TV + tl*V + joint

    // zero pad rows 68..79 (12 rows * 256 halves = 384 short8); swizzle-safe
    // because a fully-zero row is invariant under the slot permutation.
    if (tid < 384) ((short8*)(As + 68 * 256))[tid] = (short8)0;

    // ---- Phase 1: stage all K. 2176 tasks = 32 k-chunks x 68 rows.
    #pragma unroll
    for (int it = 0; it < 5; ++it) {
        int t = it * 512 + tid;
        if (t < 2176) {
            int kkc = t / 68;                  // 0..31 (16B slot index)
            int r   = t - kkc * 68;            // 0..67
            int tl  = r / 17;
            int u   = r - tl * 17;
            int c0  = kkc * 8;
            const float* gp = g + u * C_DIM + c0;
            float4 g0 = *(const float4*)gp;
            float4 g1 = *(const float4*)(gp + 4);
            float gg[8] = {g0.x, g0.y, g0.z, g0.w, g1.x, g1.y, g1.z, g1.w};
            const float* xb = xplane + tl * V;
            int mm = (u + c0) % V;
            float xv[8];
            #pragma unroll
            for (int i = 0; i < 8; ++i) {
                xv[i] = xb[(c0 + i) * TV + mm];
                mm = (mm == V - 1) ? 0 : mm + 1;
            }
            short av[8];
            #pragma unroll
            for (int i = 0; i < 8; ++i) av[i] = f2bfs(xv[i] * gg[i]);
            *(short8*)(As + r * 256 + ((kkc ^ (r & 7)) << 3)) =
                (short8){av[0], av[1], av[2], av[3], av[4], av[5], av[6], av[7]};
        }
    }
    __syncthreads();

    // ---- Phase 2: MFMA, no barriers. Wave wv owns cols [wv*32, wv*32+32).
    f32x4 acc[5][2];
    #pragma unroll
    for (int mi = 0; mi < 5; ++mi)
        #pragma unroll
        for (int ni = 0; ni < 2; ++ni)
            acc[mi][ni] = (f32x4){0.f, 0.f, 0.f, 0.f};

    #pragma unroll
    for (int kc = 0; kc < 8; ++kc) {
        short8 bfr[2];
        #pragma unroll
        for (int ni = 0; ni < 2; ++ni)
            bfr[ni] = *(const short8*)(wtb +
                ((kc * 256 + wv * 32 + ni * 16 + l15) << 5) + lq * 8);
        short8 afr[5];
        #pragma unroll
        for (int mi = 0; mi < 5; ++mi) {
            int row = mi * 16 + l15;
            afr[mi] = *(const short8*)(As + row * 256 +
                ((((kc << 2) | lq) ^ (row & 7)) << 3));
        }
        #pragma unroll
        for (int mi = 0; mi < 5; ++mi)
            #pragma unroll
            for (int ni = 0; ni < 2; ++ni)
                acc[mi][ni] = __builtin_amdgcn_mfma_f32_16x16x32_bf16(
                    afr[mi], bfr[ni], acc[mi][ni], 0, 0, 0);
    }
    __syncthreads();   // As dead; Ys live

    // ---- Phase 3: epilogue — per-wave LDS transpose, then coalesced
    //      float4 BN + residual + relu (68-float d-windows).
    float* yw = Ys + wv * 16 * YP;
    const int dbase0 = wv * 32;
    #pragma unroll
    for (int ni = 0; ni < 2; ++ni) {
        const int d_l = dbase0 + ni * 16 + l15;
        const int dm  = d_l % V;
        #pragma unroll
        for (int mi = 0; mi < 5; ++mi) {
            #pragma unroll
            for (int rg = 0; rg < 4; ++rg) {
                int row = mi * 16 + lq * 4 + rg;     // D frag: col=l15, row=lq*4+rg
                if (row < 68) {
                    int tl = row / V;
                    int u  = row - tl * V;
                    int v  = u + dm; if (v >= V) v -= V;
                    yw[l15 * YP + tl * V + v] = acc[mi][ni][rg];
                }
            }
        }
        __syncthreads();
        #pragma unroll
        for (int it = 0; it < 5; ++it) {
            int j = it * 64 + lane;                  // 272 float4 per wave-tile
            if (j < 272) {
                int dl  = j / 17;                    // 0..15
                int p4  = j - dl * 17;               // 0..16
                int d   = dbase0 + ni * 16 + dl;
                int pos = p4 * 4;
                int base = n * CTV + d * TV + tb * V + pos;
                float4 yv = *(const float4*)(yw + dl * YP + pos);
                float4 xv = *(const float4*)(x0 + base);
                float yy[4] = {yv.x, yv.y, yv.z, yv.w};
                float xx[4] = {xv.x, xv.y, xv.z, xv.w};
                int v = pos % V;
                float rr[4];
                #pragma unroll
                for (int e = 0; e < 4; ++e) {
                    float2 so = soff[v * C_DIM + d];
                    rr[e] = fmaxf(yy[e] * so.x + so.y + xx[e], 0.f);
                    if (++v == V) v = 0;
                }
                *(float4*)(out + base) = (float4){rr[0], rr[1], rr[2], rr[3]};
            }
        }
        __syncthreads();
    }
}

extern "C" void kernel_launch(void* const* d_in, const int* in_sizes, int n_in,
                              void* d_out, int out_size, void* d_ws, size_t ws_size,
                              hipStream_t stream)
{
    const float* x0    = (const float*)d_in[0];
    const float* fm    = (const float*)d_in[1];
    const float* W     = (const float*)d_in[2];
    const float* lb    = (const float*)d_in[3];
    const float* gamma = (const float*)d_in[4];
    const float* beta  = (const float*)d_in[5];
    const float* mean  = (const float*)d_in[6];
    const float* var   = (const float*)d_in[7];
    float* out = (float*)d_out;

    char* ws = (char*)d_ws;
    __hip_bfloat16* wtb = (__hip_bfloat16*)ws;
    float* g      = (float*)(ws + 131072);
    float2* soff  = (float2*)(ws + 148480);

    prep_kernel<<<256, 256, 0, stream>>>(fm, W, lb, gamma, beta, mean, var,
                                         wtb, g, soff);
    shiftgcn_kernel<<<1024, 512, 0, stream>>>(x0, wtb, g, soff, out);
}